// Round 1
// baseline (962.764 us; speedup 1.0000x reference)
//
#include <hip/hip_runtime.h>
#include <cstdint>
#include <cstddef>

#define N_NODES 100000
#define E_EDGES 1600000
#define F_IN 256
#define F_OUT 128

// ---------------- GEMM: H = in_feat @ W  ([N,256] x [256,128]) ----------------
#define BM 64
#define BK 16

__global__ __launch_bounds__(256) void gemm_kernel(const float* __restrict__ A,
                                                   const float* __restrict__ W,
                                                   float* __restrict__ H) {
    __shared__ float As[BK][BM];        // transposed A tile
    __shared__ float Bs[BK][F_OUT];
    int tid = threadIdx.x;
    int tx = tid & 15;                  // col group: 8 cols each
    int ty = tid >> 4;                  // row group: 4 rows each
    int row0 = blockIdx.x * BM;
    float acc[4][8] = {};

    for (int k0 = 0; k0 < F_IN; k0 += BK) {
        // A tile: 64 rows x 16 k. Each thread: 4 consecutive k (float4).
        {
            int r  = tid >> 2;
            int kg = (tid & 3) * 4;
            int grow = row0 + r;
            float4 v = make_float4(0.f, 0.f, 0.f, 0.f);
            if (grow < N_NODES)
                v = *reinterpret_cast<const float4*>(A + (size_t)grow * F_IN + k0 + kg);
            As[kg + 0][r] = v.x; As[kg + 1][r] = v.y;
            As[kg + 2][r] = v.z; As[kg + 3][r] = v.w;
        }
        // B tile: 16 k x 128 c = 2048 floats, 2 float4 per thread.
        {
            int i = tid * 4;
            int k = i >> 7, c = i & 127;
            *reinterpret_cast<float4*>(&Bs[k][c]) =
                *reinterpret_cast<const float4*>(W + (size_t)(k0 + k) * F_OUT + c);
            i += 1024;
            k = i >> 7; c = i & 127;
            *reinterpret_cast<float4*>(&Bs[k][c]) =
                *reinterpret_cast<const float4*>(W + (size_t)(k0 + k) * F_OUT + c);
        }
        __syncthreads();
        #pragma unroll
        for (int k = 0; k < BK; ++k) {
            float a[4], b[8];
            #pragma unroll
            for (int i = 0; i < 4; ++i) a[i] = As[k][ty * 4 + i];
            #pragma unroll
            for (int j = 0; j < 8; ++j) b[j] = Bs[k][tx * 8 + j];
            #pragma unroll
            for (int i = 0; i < 4; ++i)
                #pragma unroll
                for (int j = 0; j < 8; ++j)
                    acc[i][j] += a[i] * b[j];
        }
        __syncthreads();
    }
    #pragma unroll
    for (int i = 0; i < 4; ++i) {
        int r = row0 + ty * 4 + i;
        if (r < N_NODES) {
            #pragma unroll
            for (int j = 0; j < 8; j += 4) {
                float4 v = make_float4(acc[i][j], acc[i][j+1], acc[i][j+2], acc[i][j+3]);
                *reinterpret_cast<float4*>(H + (size_t)r * F_OUT + tx * 8 + j) = v;
            }
        }
    }
}

// ---------------- el/er: per-node attention logits ----------------
__global__ __launch_bounds__(256) void elr_kernel(const float* __restrict__ H,
                                                  const float* __restrict__ attn_l,
                                                  const float* __restrict__ attn_r,
                                                  float* __restrict__ el,
                                                  float* __restrict__ er) {
    int wid    = (blockIdx.x * blockDim.x + threadIdx.x) >> 6;
    int lane   = threadIdx.x & 63;
    int nwaves = (gridDim.x * blockDim.x) >> 6;
    float al0 = attn_l[lane], al1 = attn_l[lane + 64];
    float ar0 = attn_r[lane], ar1 = attn_r[lane + 64];
    for (int n = wid; n < N_NODES; n += nwaves) {
        float h0 = H[(size_t)n * 128 + lane];
        float h1 = H[(size_t)n * 128 + lane + 64];
        float l = h0 * al0 + h1 * al1;
        float r = h0 * ar0 + h1 * ar1;
        #pragma unroll
        for (int off = 32; off; off >>= 1) {
            l += __shfl_down(l, off);
            r += __shfl_down(r, off);
        }
        if (lane == 0) { el[n] = l; er[n] = r; }
    }
}

// ---------------- edge softmax helpers ----------------
__device__ __forceinline__ unsigned enc_f(float x) {
    unsigned b = __float_as_uint(x);
    return (b & 0x80000000u) ? ~b : (b | 0x80000000u);
}
__device__ __forceinline__ float dec_f(unsigned k) {
    unsigned b = (k & 0x80000000u) ? (k ^ 0x80000000u) : ~k;
    return __uint_as_float(b);
}

__global__ __launch_bounds__(256) void edge1_kernel(const int* __restrict__ src,
                                                    const int* __restrict__ dst,
                                                    const float* __restrict__ el,
                                                    const float* __restrict__ er,
                                                    float* __restrict__ ebuf,
                                                    unsigned* __restrict__ menc) {
    int i = blockIdx.x * blockDim.x + threadIdx.x;
    if (i >= E_EDGES) return;
    int d = dst[i];
    float x = el[src[i]] + er[d];
    x = x > 0.f ? x : 0.2f * x;          // leaky_relu(0.2)
    ebuf[i] = x;
    atomicMax(&menc[d], enc_f(x));
}

__global__ __launch_bounds__(256) void edge2_kernel(const int* __restrict__ dst,
                                                    float* __restrict__ ebuf,
                                                    const unsigned* __restrict__ menc,
                                                    float* __restrict__ ssum) {
    int i = blockIdx.x * blockDim.x + threadIdx.x;
    if (i >= E_EDGES) return;
    int d = dst[i];
    float ex = expf(ebuf[i] - dec_f(menc[d]));
    ebuf[i] = ex;
    atomicAdd(&ssum[d], ex);
}

// ---------------- aggregation: agg[dst] += alpha * h[src] ----------------
__global__ __launch_bounds__(256) void agg_kernel(const int* __restrict__ src,
                                                  const int* __restrict__ dst,
                                                  const float* __restrict__ ebuf,
                                                  const float* __restrict__ ssum,
                                                  const float* __restrict__ H,
                                                  float* __restrict__ agg) {
    int wid    = (blockIdx.x * blockDim.x + threadIdx.x) >> 6;
    int lane   = threadIdx.x & 63;
    int nwaves = (gridDim.x * blockDim.x) >> 6;
    for (int e = wid; e < E_EDGES; e += nwaves) {
        int s_ = src[e], d_ = dst[e];
        float alpha = ebuf[e] / ssum[d_];    // s>0 for any existing edge
        float h0 = H[(size_t)s_ * 128 + lane];
        float h1 = H[(size_t)s_ * 128 + lane + 64];
        atomicAdd(&agg[(size_t)d_ * 128 + lane],      alpha * h0);
        atomicAdd(&agg[(size_t)d_ * 128 + lane + 64], alpha * h1);
    }
}

// ---------------- epilogue: bias -> relu -> fc -> sigmoid ----------------
__global__ __launch_bounds__(256) void final_kernel(const float* __restrict__ agg,
                                                    const float* __restrict__ bias,
                                                    const float* __restrict__ fcw,
                                                    const float* __restrict__ fcb,
                                                    float* __restrict__ out) {
    int wid    = (blockIdx.x * blockDim.x + threadIdx.x) >> 6;
    int lane   = threadIdx.x & 63;
    int nwaves = (gridDim.x * blockDim.x) >> 6;
    float b0 = bias[lane], b1 = bias[lane + 64];
    float w00 = fcw[lane * 2 + 0],        w01 = fcw[lane * 2 + 1];
    float w10 = fcw[(lane + 64) * 2 + 0], w11 = fcw[(lane + 64) * 2 + 1];
    float fb0 = fcb[0], fb1 = fcb[1];
    for (int n = wid; n < N_NODES; n += nwaves) {
        float v0 = fmaxf(agg[(size_t)n * 128 + lane]      + b0, 0.f);
        float v1 = fmaxf(agg[(size_t)n * 128 + lane + 64] + b1, 0.f);
        float d0 = v0 * w00 + v1 * w10;
        float d1 = v0 * w01 + v1 * w11;
        #pragma unroll
        for (int off = 32; off; off >>= 1) {
            d0 += __shfl_down(d0, off);
            d1 += __shfl_down(d1, off);
        }
        if (lane == 0) {
            out[(size_t)n * 2 + 0] = 1.f / (1.f + expf(-(d0 + fb0)));
            out[(size_t)n * 2 + 1] = 1.f / (1.f + expf(-(d1 + fb1)));
        }
    }
}

extern "C" void kernel_launch(void* const* d_in, const int* in_sizes, int n_in,
                              void* d_out, int out_size, void* d_ws, size_t ws_size,
                              hipStream_t stream) {
    const float* in_feat = (const float*)d_in[0];
    const float* W       = (const float*)d_in[1];
    const float* attn_l  = (const float*)d_in[2];
    const float* attn_r  = (const float*)d_in[3];
    const float* bias    = (const float*)d_in[4];
    const float* fc_w    = (const float*)d_in[5];
    const float* fc_b    = (const float*)d_in[6];
    const int*   src     = (const int*)d_in[7];
    const int*   dst     = (const int*)d_in[8];
    float* out = (float*)d_out;

    char* p = (char*)d_ws;
    float*    H    = (float*)p;    p += (size_t)N_NODES * 128 * sizeof(float);
    float*    AGG  = (float*)p;    p += (size_t)N_NODES * 128 * sizeof(float);
    float*    EL   = (float*)p;    p += (size_t)N_NODES * sizeof(float);
    float*    ER   = (float*)p;    p += (size_t)N_NODES * sizeof(float);
    unsigned* MENC = (unsigned*)p; p += (size_t)N_NODES * sizeof(unsigned);
    float*    SSUM = (float*)p;    p += (size_t)N_NODES * sizeof(float);
    float*    EBUF = (float*)p;    p += (size_t)E_EDGES * sizeof(float);

    hipMemsetAsync(AGG,  0, (size_t)N_NODES * 128 * sizeof(float), stream);
    hipMemsetAsync(MENC, 0, (size_t)N_NODES * sizeof(unsigned), stream);
    hipMemsetAsync(SSUM, 0, (size_t)N_NODES * sizeof(float), stream);

    gemm_kernel<<<(N_NODES + BM - 1) / BM, 256, 0, stream>>>(in_feat, W, H);
    elr_kernel<<<1024, 256, 0, stream>>>(H, attn_l, attn_r, EL, ER);
    edge1_kernel<<<(E_EDGES + 255) / 256, 256, 0, stream>>>(src, dst, EL, ER, EBUF, MENC);
    edge2_kernel<<<(E_EDGES + 255) / 256, 256, 0, stream>>>(dst, EBUF, MENC, SSUM);
    agg_kernel<<<4096, 256, 0, stream>>>(src, dst, EBUF, SSUM, H, AGG);
    final_kernel<<<1024, 256, 0, stream>>>(AGG, bias, fc_w, fc_b, out);
}

// Round 2
// 461.195 us; speedup vs baseline: 2.0875x; 2.0875x over previous
//
#include <hip/hip_runtime.h>
#include <cstdint>
#include <cstddef>

#define N_NODES 100000
#define E_EDGES 1600000
#define F_IN 256
#define F_OUT 128
#define NB 391   // ceil(N_NODES/256)

// ---------------- GEMM: H = in_feat @ W  ([N,256] x [256,128]) ----------------
#define BM 64
#define BK 16

__global__ __launch_bounds__(256) void gemm_kernel(const float* __restrict__ A,
                                                   const float* __restrict__ W,
                                                   float* __restrict__ H) {
    __shared__ float As[BK][BM];
    __shared__ float Bs[BK][F_OUT];
    int tid = threadIdx.x;
    int tx = tid & 15;
    int ty = tid >> 4;
    int row0 = blockIdx.x * BM;
    float acc[4][8] = {};

    for (int k0 = 0; k0 < F_IN; k0 += BK) {
        {
            int r  = tid >> 2;
            int kg = (tid & 3) * 4;
            int grow = row0 + r;
            float4 v = make_float4(0.f, 0.f, 0.f, 0.f);
            if (grow < N_NODES)
                v = *reinterpret_cast<const float4*>(A + (size_t)grow * F_IN + k0 + kg);
            As[kg + 0][r] = v.x; As[kg + 1][r] = v.y;
            As[kg + 2][r] = v.z; As[kg + 3][r] = v.w;
        }
        {
            int i = tid * 4;
            int k = i >> 7, c = i & 127;
            *reinterpret_cast<float4*>(&Bs[k][c]) =
                *reinterpret_cast<const float4*>(W + (size_t)(k0 + k) * F_OUT + c);
            i += 1024;
            k = i >> 7; c = i & 127;
            *reinterpret_cast<float4*>(&Bs[k][c]) =
                *reinterpret_cast<const float4*>(W + (size_t)(k0 + k) * F_OUT + c);
        }
        __syncthreads();
        #pragma unroll
        for (int k = 0; k < BK; ++k) {
            float a[4], b[8];
            #pragma unroll
            for (int i = 0; i < 4; ++i) a[i] = As[k][ty * 4 + i];
            #pragma unroll
            for (int j = 0; j < 8; ++j) b[j] = Bs[k][tx * 8 + j];
            #pragma unroll
            for (int i = 0; i < 4; ++i)
                #pragma unroll
                for (int j = 0; j < 8; ++j)
                    acc[i][j] += a[i] * b[j];
        }
        __syncthreads();
    }
    #pragma unroll
    for (int i = 0; i < 4; ++i) {
        int r = row0 + ty * 4 + i;
        if (r < N_NODES) {
            #pragma unroll
            for (int j = 0; j < 8; j += 4) {
                float4 v = make_float4(acc[i][j], acc[i][j+1], acc[i][j+2], acc[i][j+3]);
                *reinterpret_cast<float4*>(H + (size_t)r * F_OUT + tx * 8 + j) = v;
            }
        }
    }
}

// ---------------- el/er: per-node attention logits ----------------
__global__ __launch_bounds__(256) void elr_kernel(const float* __restrict__ H,
                                                  const float* __restrict__ attn_l,
                                                  const float* __restrict__ attn_r,
                                                  float* __restrict__ el,
                                                  float* __restrict__ er) {
    int wid    = (blockIdx.x * blockDim.x + threadIdx.x) >> 6;
    int lane   = threadIdx.x & 63;
    int nwaves = (gridDim.x * blockDim.x) >> 6;
    float al0 = attn_l[lane], al1 = attn_l[lane + 64];
    float ar0 = attn_r[lane], ar1 = attn_r[lane + 64];
    for (int n = wid; n < N_NODES; n += nwaves) {
        float h0 = H[(size_t)n * 128 + lane];
        float h1 = H[(size_t)n * 128 + lane + 64];
        float l = h0 * al0 + h1 * al1;
        float r = h0 * ar0 + h1 * ar1;
        #pragma unroll
        for (int off = 32; off; off >>= 1) {
            l += __shfl_down(l, off);
            r += __shfl_down(r, off);
        }
        if (lane == 0) { el[n] = l; er[n] = r; }
    }
}

// ---------------- CSR build ----------------
__global__ __launch_bounds__(256) void k_count(const int* __restrict__ dst,
                                               int* __restrict__ deg) {
    int i = blockIdx.x * blockDim.x + threadIdx.x;
    if (i >= E_EDGES) return;
    atomicAdd(&deg[dst[i]], 1);
}

__global__ __launch_bounds__(256) void k_bsum(const int* __restrict__ deg,
                                              int* __restrict__ bsum) {
    __shared__ int s[256];
    int i = blockIdx.x * 256 + threadIdx.x;
    s[threadIdx.x] = (i < N_NODES) ? deg[i] : 0;
    __syncthreads();
    #pragma unroll
    for (int off = 128; off; off >>= 1) {
        if (threadIdx.x < off) s[threadIdx.x] += s[threadIdx.x + off];
        __syncthreads();
    }
    if (threadIdx.x == 0) bsum[blockIdx.x] = s[0];
}

__global__ __launch_bounds__(512) void k_bscan(const int* __restrict__ bsum,
                                               int* __restrict__ boff) {
    __shared__ int s[512];
    int t = threadIdx.x;
    s[t] = (t < NB) ? bsum[t] : 0;
    __syncthreads();
    for (int off = 1; off < 512; off <<= 1) {
        int v = (t >= off) ? s[t - off] : 0;
        __syncthreads();
        s[t] += v;
        __syncthreads();
    }
    if (t < NB) boff[t] = (t ? s[t - 1] : 0);
}

__global__ __launch_bounds__(256) void k_rowptr(const int* __restrict__ deg,
                                                const int* __restrict__ boff,
                                                int* __restrict__ rowptr,
                                                int* __restrict__ cursor) {
    __shared__ int s[256];
    int i = blockIdx.x * 256 + threadIdx.x;
    int t = threadIdx.x;
    int d = (i < N_NODES) ? deg[i] : 0;
    s[t] = d;
    __syncthreads();
    for (int off = 1; off < 256; off <<= 1) {
        int v = (t >= off) ? s[t - off] : 0;
        __syncthreads();
        s[t] += v;
        __syncthreads();
    }
    if (i < N_NODES) {
        int excl = s[t] - d + boff[blockIdx.x];
        rowptr[i] = excl;
        cursor[i] = excl;
    }
}

__global__ __launch_bounds__(256) void k_scatter(const int* __restrict__ src,
                                                 const int* __restrict__ dst,
                                                 int* __restrict__ cursor,
                                                 int* __restrict__ esrc) {
    int i = blockIdx.x * blockDim.x + threadIdx.x;
    if (i >= E_EDGES) return;
    int p = atomicAdd(&cursor[dst[i]], 1);
    esrc[p] = src[i];
}

// ---------------- fused: edge softmax + aggregation + head ----------------
__global__ __launch_bounds__(256) void agg_fused(const int* __restrict__ rowptr,
                                                 const int* __restrict__ deg,
                                                 const int* __restrict__ esrc,
                                                 const float* __restrict__ el,
                                                 const float* __restrict__ er,
                                                 const float* __restrict__ H,
                                                 const float* __restrict__ bias,
                                                 const float* __restrict__ fcw,
                                                 const float* __restrict__ fcb,
                                                 float* __restrict__ out) {
    int wid  = (blockIdx.x * blockDim.x + threadIdx.x) >> 6;
    int lane = threadIdx.x & 63;
    if (wid >= N_NODES) return;
    int n = wid;
    int start = rowptr[n];
    int dg    = deg[n];
    float ern = er[n];

    // pass A: segment max
    float m = -3.4e38f;
    for (int base = 0; base < dg; base += 64) {
        int j = base + lane;
        float x = -3.4e38f;
        if (j < dg) {
            float t = el[esrc[start + j]] + ern;
            x = t > 0.f ? t : 0.2f * t;
        }
        #pragma unroll
        for (int off = 32; off; off >>= 1) x = fmaxf(x, __shfl_xor(x, off));
        m = fmaxf(m, x);
    }

    // pass B: accumulate sum(exp) and sum(exp * h[src])
    const float2* __restrict__ H2 = (const float2*)H;
    float2 acc = make_float2(0.f, 0.f);
    float ssum = 0.f;
    for (int base = 0; base < dg; base += 64) {
        int cnt = min(64, dg - base);
        int sid = 0;
        float ex = 0.f;
        if (lane < cnt) {
            sid = esrc[start + base + lane];
            float t = el[sid] + ern;
            t = t > 0.f ? t : 0.2f * t;
            ex = expf(t - m);
        }
        for (int q = 0; q < cnt; ++q) {
            float exq = __shfl(ex, q);
            int   sq  = __shfl(sid, q);
            float2 hv = H2[(size_t)sq * 64 + lane];
            acc.x += exq * hv.x;
            acc.y += exq * hv.y;
            ssum  += exq;
        }
    }

    float scale = ssum > 0.f ? 1.f / ssum : 0.f;
    float2 bv = ((const float2*)bias)[lane];
    float v0 = fmaxf(acc.x * scale + bv.x, 0.f);
    float v1 = fmaxf(acc.y * scale + bv.y, 0.f);
    float4 wv = ((const float4*)fcw)[lane];  // fcw[2l][0..1], fcw[2l+1][0..1]
    float d0 = v0 * wv.x + v1 * wv.z;
    float d1 = v0 * wv.y + v1 * wv.w;
    #pragma unroll
    for (int off = 32; off; off >>= 1) {
        d0 += __shfl_down(d0, off);
        d1 += __shfl_down(d1, off);
    }
    if (lane == 0) {
        float b0 = fcb[0], b1 = fcb[1];
        out[(size_t)n * 2 + 0] = 1.f / (1.f + expf(-(d0 + b0)));
        out[(size_t)n * 2 + 1] = 1.f / (1.f + expf(-(d1 + b1)));
    }
}

extern "C" void kernel_launch(void* const* d_in, const int* in_sizes, int n_in,
                              void* d_out, int out_size, void* d_ws, size_t ws_size,
                              hipStream_t stream) {
    const float* in_feat = (const float*)d_in[0];
    const float* W       = (const float*)d_in[1];
    const float* attn_l  = (const float*)d_in[2];
    const float* attn_r  = (const float*)d_in[3];
    const float* bias    = (const float*)d_in[4];
    const float* fc_w    = (const float*)d_in[5];
    const float* fc_b    = (const float*)d_in[6];
    const int*   src     = (const int*)d_in[7];
    const int*   dst     = (const int*)d_in[8];
    float* out = (float*)d_out;

    char* p = (char*)d_ws;
    float* H      = (float*)p; p += (size_t)N_NODES * 128 * sizeof(float);
    float* EL     = (float*)p; p += (size_t)N_NODES * sizeof(float);
    float* ER     = (float*)p; p += (size_t)N_NODES * sizeof(float);
    int*   DEG    = (int*)p;   p += (size_t)N_NODES * sizeof(int);
    int*   ROWPTR = (int*)p;   p += (size_t)N_NODES * sizeof(int);
    int*   CURSOR = (int*)p;   p += (size_t)N_NODES * sizeof(int);
    int*   BSUM   = (int*)p;   p += 512 * sizeof(int);
    int*   BOFF   = (int*)p;   p += 512 * sizeof(int);
    int*   ESRC   = (int*)p;   p += (size_t)E_EDGES * sizeof(int);

    hipMemsetAsync(DEG, 0, (size_t)N_NODES * sizeof(int), stream);

    gemm_kernel<<<(N_NODES + BM - 1) / BM, 256, 0, stream>>>(in_feat, W, H);
    elr_kernel<<<1024, 256, 0, stream>>>(H, attn_l, attn_r, EL, ER);

    k_count  <<<(E_EDGES + 255) / 256, 256, 0, stream>>>(dst, DEG);
    k_bsum   <<<NB, 256, 0, stream>>>(DEG, BSUM);
    k_bscan  <<<1, 512, 0, stream>>>(BSUM, BOFF);
    k_rowptr <<<NB, 256, 0, stream>>>(DEG, BOFF, ROWPTR, CURSOR);
    k_scatter<<<(E_EDGES + 255) / 256, 256, 0, stream>>>(src, dst, CURSOR, ESRC);

    agg_fused<<<(N_NODES * 64 + 255) / 256, 256, 0, stream>>>(
        ROWPTR, DEG, ESRC, EL, ER, H, bias, fc_w, fc_b, out);
}

// Round 3
// 363.329 us; speedup vs baseline: 2.6498x; 1.2694x over previous
//
#include <hip/hip_runtime.h>
#include <cstdint>
#include <cstddef>

#define N_NODES 100000
#define E_EDGES 1600000
#define F_IN 256
#define F_OUT 128
#define NB 391   // ceil(N_NODES/256)

typedef __attribute__((ext_vector_type(8))) short  short8v;
typedef __attribute__((ext_vector_type(4))) float  float4v;

__device__ __forceinline__ unsigned short f2bf(float x) {
    union { float f; unsigned u; } v; v.f = x;
    unsigned r = v.u + 0x7fffu + ((v.u >> 16) & 1u);   // RNE
    return (unsigned short)(r >> 16);
}

// ---------------- W transpose+convert: Wt[j][k] = bf16(W[k][j]) ----------------
__global__ __launch_bounds__(256) void wcvt_kernel(const float* __restrict__ W,
                                                   unsigned short* __restrict__ Wt) {
    int t = blockIdx.x * 256 + threadIdx.x;
    if (t >= F_IN * F_OUT) return;
    int k = t >> 7, j = t & 127;
    Wt[j * F_IN + k] = f2bf(W[t]);
}

// ---------------- MFMA GEMM + fused el/er + bf16 H store ----------------
// block: 256 thr (4 waves), tile 64 rows x 128 cols, K staged in 64-chunks.
__global__ __launch_bounds__(256) void gemm_mfma(const float* __restrict__ A,
                                                 const unsigned short* __restrict__ Wt,
                                                 const float* __restrict__ attn_l,
                                                 const float* __restrict__ attn_r,
                                                 unsigned short* __restrict__ Hb,
                                                 float* __restrict__ el,
                                                 float* __restrict__ er) {
    __shared__ unsigned short As[64 * 64];    // [row][k], XOR-swizzled
    __shared__ unsigned short Bs[128 * 64];   // [j][k],   XOR-swizzled
    int tid  = threadIdx.x;
    int wave = tid >> 6, lane = tid & 63;
    int g = lane >> 4, c = lane & 15;
    int row0 = blockIdx.x * 64;
    float4v acc[8] = {};

    for (int k0 = 0; k0 < F_IN; k0 += 64) {
        // stage A tile: 64 rows x 64 k, f32 -> bf16
        {
            int r  = tid >> 2;
            int ks = (tid & 3) * 16;
            int grow = row0 + r;
            unsigned short tmp[16];
            if (grow < N_NODES) {
                const float* ap = A + (size_t)grow * F_IN + k0 + ks;
                #pragma unroll
                for (int i = 0; i < 4; ++i) {
                    float4 v = reinterpret_cast<const float4*>(ap)[i];
                    tmp[i*4+0] = f2bf(v.x); tmp[i*4+1] = f2bf(v.y);
                    tmp[i*4+2] = f2bf(v.z); tmp[i*4+3] = f2bf(v.w);
                }
            } else {
                #pragma unroll
                for (int i = 0; i < 16; ++i) tmp[i] = 0;
            }
            int u0 = (r * 64 + ks) ^ ((r & 7) << 3);
            int u1 = (r * 64 + ks + 8) ^ ((r & 7) << 3);
            *reinterpret_cast<short8v*>(&As[u0]) = *reinterpret_cast<short8v*>(&tmp[0]);
            *reinterpret_cast<short8v*>(&As[u1]) = *reinterpret_cast<short8v*>(&tmp[8]);
        }
        // stage B tile: 128 j x 64 k (bf16 from Wt)
        {
            int j   = tid >> 1;
            int ks2 = (tid & 1) * 32;
            const short8v* wp = reinterpret_cast<const short8v*>(Wt + (size_t)j * F_IN + k0 + ks2);
            #pragma unroll
            for (int i = 0; i < 4; ++i) {
                int u = (j * 64 + ks2 + 8 * i) ^ ((j & 7) << 3);
                *reinterpret_cast<short8v*>(&Bs[u]) = wp[i];
            }
        }
        __syncthreads();
        #pragma unroll
        for (int ks = 0; ks < 2; ++ks) {
            int arow = wave * 16 + c;
            int aoff = (arow * 64 + ks * 32 + g * 8) ^ ((arow & 7) << 3);
            short8v af = *reinterpret_cast<short8v*>(&As[aoff]);
            #pragma unroll
            for (int nt = 0; nt < 8; ++nt) {
                int j = nt * 16 + c;
                int boff = (j * 64 + ks * 32 + g * 8) ^ ((j & 7) << 3);
                short8v bf = *reinterpret_cast<short8v*>(&Bs[boff]);
                acc[nt] = __builtin_amdgcn_mfma_f32_16x16x32_bf16(af, bf, acc[nt], 0, 0, 0);
            }
        }
        __syncthreads();
    }

    // epilogue: store bf16 H, compute el/er from f32 accumulators
    float al[8], ar[8];
    #pragma unroll
    for (int nt = 0; nt < 8; ++nt) {
        al[nt] = attn_l[nt * 16 + c];
        ar[nt] = attn_r[nt * 16 + c];
    }
    #pragma unroll
    for (int r = 0; r < 4; ++r) {
        int grow = row0 + wave * 16 + g * 4 + r;
        float sl = 0.f, sr = 0.f;
        #pragma unroll
        for (int nt = 0; nt < 8; ++nt) {
            float h = acc[nt][r];
            sl += h * al[nt];
            sr += h * ar[nt];
        }
        if (grow < N_NODES) {
            #pragma unroll
            for (int nt = 0; nt < 8; ++nt)
                Hb[(size_t)grow * F_OUT + nt * 16 + c] = f2bf(acc[nt][r]);
        }
        #pragma unroll
        for (int off = 1; off < 16; off <<= 1) {
            sl += __shfl_xor(sl, off);
            sr += __shfl_xor(sr, off);
        }
        if (c == 0 && grow < N_NODES) { el[grow] = sl; er[grow] = sr; }
    }
}

// ---------------- CSR build ----------------
__global__ __launch_bounds__(256) void k_count(const int* __restrict__ dst,
                                               int* __restrict__ deg) {
    int i = blockIdx.x * blockDim.x + threadIdx.x;
    if (i >= E_EDGES) return;
    atomicAdd(&deg[dst[i]], 1);
}

__global__ __launch_bounds__(256) void k_bsum(const int* __restrict__ deg,
                                              int* __restrict__ bsum) {
    __shared__ int s[256];
    int i = blockIdx.x * 256 + threadIdx.x;
    s[threadIdx.x] = (i < N_NODES) ? deg[i] : 0;
    __syncthreads();
    #pragma unroll
    for (int off = 128; off; off >>= 1) {
        if (threadIdx.x < off) s[threadIdx.x] += s[threadIdx.x + off];
        __syncthreads();
    }
    if (threadIdx.x == 0) bsum[blockIdx.x] = s[0];
}

__global__ __launch_bounds__(512) void k_bscan(const int* __restrict__ bsum,
                                               int* __restrict__ boff) {
    __shared__ int s[512];
    int t = threadIdx.x;
    s[t] = (t < NB) ? bsum[t] : 0;
    __syncthreads();
    for (int off = 1; off < 512; off <<= 1) {
        int v = (t >= off) ? s[t - off] : 0;
        __syncthreads();
        s[t] += v;
        __syncthreads();
    }
    if (t < NB) boff[t] = (t ? s[t - 1] : 0);
}

__global__ __launch_bounds__(256) void k_rowptr(const int* __restrict__ deg,
                                                const int* __restrict__ boff,
                                                int* __restrict__ rowptr,
                                                int* __restrict__ cursor) {
    __shared__ int s[256];
    int i = blockIdx.x * 256 + threadIdx.x;
    int t = threadIdx.x;
    int d = (i < N_NODES) ? deg[i] : 0;
    s[t] = d;
    __syncthreads();
    for (int off = 1; off < 256; off <<= 1) {
        int v = (t >= off) ? s[t - off] : 0;
        __syncthreads();
        s[t] += v;
        __syncthreads();
    }
    if (i < N_NODES) {
        int excl = s[t] - d + boff[blockIdx.x];
        rowptr[i] = excl;
        cursor[i] = excl;
    }
}

__global__ __launch_bounds__(256) void k_scatter(const int* __restrict__ src,
                                                 const int* __restrict__ dst,
                                                 int* __restrict__ cursor,
                                                 int* __restrict__ esrc) {
    int i = blockIdx.x * blockDim.x + threadIdx.x;
    if (i >= E_EDGES) return;
    int p = atomicAdd(&cursor[dst[i]], 1);
    esrc[p] = src[i];
}

// ---------------- fused: edge softmax + aggregation + head (bf16 H) ----------------
__global__ __launch_bounds__(256) void agg_fused(const int* __restrict__ rowptr,
                                                 const int* __restrict__ deg,
                                                 const int* __restrict__ esrc,
                                                 const float* __restrict__ el,
                                                 const float* __restrict__ er,
                                                 const unsigned int* __restrict__ H2,
                                                 const float* __restrict__ bias,
                                                 const float* __restrict__ fcw,
                                                 const float* __restrict__ fcb,
                                                 float* __restrict__ out) {
    int wid  = (blockIdx.x * blockDim.x + threadIdx.x) >> 6;
    int lane = threadIdx.x & 63;
    if (wid >= N_NODES) return;
    int n = wid;
    int start = rowptr[n];
    int dg    = deg[n];
    float ern = er[n];

    // pass A: segment max
    float m = -3.4e38f;
    for (int base = 0; base < dg; base += 64) {
        int j = base + lane;
        float x = -3.4e38f;
        if (j < dg) {
            float t = el[esrc[start + j]] + ern;
            x = t > 0.f ? t : 0.2f * t;
        }
        #pragma unroll
        for (int off = 32; off; off >>= 1) x = fmaxf(x, __shfl_xor(x, off));
        m = fmaxf(m, x);
    }

    // pass B: sum(exp) and sum(exp * h[src]), h gathered as bf16 pairs
    float2 acc = make_float2(0.f, 0.f);
    float ssum = 0.f;
    for (int base = 0; base < dg; base += 64) {
        int cnt = min(64, dg - base);
        int sid = 0;
        float ex = 0.f;
        if (lane < cnt) {
            sid = esrc[start + base + lane];
            float t = el[sid] + ern;
            t = t > 0.f ? t : 0.2f * t;
            ex = expf(t - m);
        }
        for (int q = 0; q < cnt; ++q) {
            float exq = __shfl(ex, q);
            int   sq  = __shfl(sid, q);
            unsigned int hv = H2[(size_t)sq * 64 + lane];
            float h0 = __uint_as_float(hv << 16);
            float h1 = __uint_as_float(hv & 0xffff0000u);
            acc.x += exq * h0;
            acc.y += exq * h1;
            ssum  += exq;
        }
    }

    float scale = ssum > 0.f ? 1.f / ssum : 0.f;
    float2 bv = ((const float2*)bias)[lane];
    float v0 = fmaxf(acc.x * scale + bv.x, 0.f);
    float v1 = fmaxf(acc.y * scale + bv.y, 0.f);
    float4 wv = ((const float4*)fcw)[lane];
    float d0 = v0 * wv.x + v1 * wv.z;
    float d1 = v0 * wv.y + v1 * wv.w;
    #pragma unroll
    for (int off = 32; off; off >>= 1) {
        d0 += __shfl_down(d0, off);
        d1 += __shfl_down(d1, off);
    }
    if (lane == 0) {
        out[(size_t)n * 2 + 0] = 1.f / (1.f + expf(-(d0 + fcb[0])));
        out[(size_t)n * 2 + 1] = 1.f / (1.f + expf(-(d1 + fcb[1])));
    }
}

extern "C" void kernel_launch(void* const* d_in, const int* in_sizes, int n_in,
                              void* d_out, int out_size, void* d_ws, size_t ws_size,
                              hipStream_t stream) {
    const float* in_feat = (const float*)d_in[0];
    const float* W       = (const float*)d_in[1];
    const float* attn_l  = (const float*)d_in[2];
    const float* attn_r  = (const float*)d_in[3];
    const float* bias    = (const float*)d_in[4];
    const float* fc_w    = (const float*)d_in[5];
    const float* fc_b    = (const float*)d_in[6];
    const int*   src     = (const int*)d_in[7];
    const int*   dst     = (const int*)d_in[8];
    float* out = (float*)d_out;

    char* p = (char*)d_ws;
    unsigned short* HB  = (unsigned short*)p; p += (size_t)N_NODES * F_OUT * sizeof(unsigned short);
    unsigned short* WT  = (unsigned short*)p; p += (size_t)F_IN * F_OUT * sizeof(unsigned short);
    float* EL     = (float*)p; p += (size_t)N_NODES * sizeof(float);
    float* ER     = (float*)p; p += (size_t)N_NODES * sizeof(float);
    int*   DEG    = (int*)p;   p += (size_t)N_NODES * sizeof(int);
    int*   ROWPTR = (int*)p;   p += (size_t)N_NODES * sizeof(int);
    int*   CURSOR = (int*)p;   p += (size_t)N_NODES * sizeof(int);
    int*   BSUM   = (int*)p;   p += 512 * sizeof(int);
    int*   BOFF   = (int*)p;   p += 512 * sizeof(int);
    int*   ESRC   = (int*)p;   p += (size_t)E_EDGES * sizeof(int);

    hipMemsetAsync(DEG, 0, (size_t)N_NODES * sizeof(int), stream);

    wcvt_kernel<<<(F_IN * F_OUT + 255) / 256, 256, 0, stream>>>(W, WT);
    gemm_mfma<<<(N_NODES + 63) / 64, 256, 0, stream>>>(in_feat, WT, attn_l, attn_r, HB, EL, ER);

    k_count  <<<(E_EDGES + 255) / 256, 256, 0, stream>>>(dst, DEG);
    k_bsum   <<<NB, 256, 0, stream>>>(DEG, BSUM);
    k_bscan  <<<1, 512, 0, stream>>>(BSUM, BOFF);
    k_rowptr <<<NB, 256, 0, stream>>>(DEG, BOFF, ROWPTR, CURSOR);
    k_scatter<<<(E_EDGES + 255) / 256, 256, 0, stream>>>(src, dst, CURSOR, ESRC);

    agg_fused<<<(N_NODES * 64 + 255) / 256, 256, 0, stream>>>(
        ROWPTR, DEG, ESRC, EL, ER, (const unsigned int*)HB, bias, fc_w, fc_b, out);
}

// Round 4
// 159.715 us; speedup vs baseline: 6.0280x; 2.2749x over previous
//
#include <hip/hip_runtime.h>
#include <cstdint>
#include <cstddef>

#define N_NODES 100000
#define E_EDGES 1600000
#define F_IN 256
#define F_OUT 128
#define NBKT 391      // ceil(N_NODES/256) buckets of 256 nodes
#define OBCAP 5120    // per-bucket LDS sort capacity (mean 4096, +16 sigma)

typedef __attribute__((ext_vector_type(8))) short  short8v;
typedef __attribute__((ext_vector_type(4))) float  float4v;

__device__ __forceinline__ unsigned short f2bf(float x) {
    union { float f; unsigned u; } v; v.f = x;
    unsigned r = v.u + 0x7fffu + ((v.u >> 16) & 1u);   // RNE
    return (unsigned short)(r >> 16);
}

// ---------------- W transpose+convert: Wt[j][k] = bf16(W[k][j]) ----------------
__global__ __launch_bounds__(256) void wcvt_kernel(const float* __restrict__ W,
                                                   unsigned short* __restrict__ Wt) {
    int t = blockIdx.x * 256 + threadIdx.x;
    if (t >= F_IN * F_OUT) return;
    int k = t >> 7, j = t & 127;
    Wt[j * F_IN + k] = f2bf(W[t]);
}

// ---------------- MFMA GEMM + fused el/er + bf16 H store ----------------
__global__ __launch_bounds__(256) void gemm_mfma(const float* __restrict__ A,
                                                 const unsigned short* __restrict__ Wt,
                                                 const float* __restrict__ attn_l,
                                                 const float* __restrict__ attn_r,
                                                 unsigned short* __restrict__ Hb,
                                                 float* __restrict__ el,
                                                 float* __restrict__ er) {
    __shared__ unsigned short As[64 * 64];
    __shared__ unsigned short Bs[128 * 64];
    int tid  = threadIdx.x;
    int wave = tid >> 6, lane = tid & 63;
    int g = lane >> 4, c = lane & 15;
    int row0 = blockIdx.x * 64;
    float4v acc[8] = {};

    for (int k0 = 0; k0 < F_IN; k0 += 64) {
        {
            int r  = tid >> 2;
            int ks = (tid & 3) * 16;
            int grow = row0 + r;
            unsigned short tmp[16];
            if (grow < N_NODES) {
                const float* ap = A + (size_t)grow * F_IN + k0 + ks;
                #pragma unroll
                for (int i = 0; i < 4; ++i) {
                    float4 v = reinterpret_cast<const float4*>(ap)[i];
                    tmp[i*4+0] = f2bf(v.x); tmp[i*4+1] = f2bf(v.y);
                    tmp[i*4+2] = f2bf(v.z); tmp[i*4+3] = f2bf(v.w);
                }
            } else {
                #pragma unroll
                for (int i = 0; i < 16; ++i) tmp[i] = 0;
            }
            int u0 = (r * 64 + ks) ^ ((r & 7) << 3);
            int u1 = (r * 64 + ks + 8) ^ ((r & 7) << 3);
            *reinterpret_cast<short8v*>(&As[u0]) = *reinterpret_cast<short8v*>(&tmp[0]);
            *reinterpret_cast<short8v*>(&As[u1]) = *reinterpret_cast<short8v*>(&tmp[8]);
        }
        {
            int j   = tid >> 1;
            int ks2 = (tid & 1) * 32;
            const short8v* wp = reinterpret_cast<const short8v*>(Wt + (size_t)j * F_IN + k0 + ks2);
            #pragma unroll
            for (int i = 0; i < 4; ++i) {
                int u = (j * 64 + ks2 + 8 * i) ^ ((j & 7) << 3);
                *reinterpret_cast<short8v*>(&Bs[u]) = wp[i];
            }
        }
        __syncthreads();
        #pragma unroll
        for (int ks = 0; ks < 2; ++ks) {
            int arow = wave * 16 + c;
            int aoff = (arow * 64 + ks * 32 + g * 8) ^ ((arow & 7) << 3);
            short8v af = *reinterpret_cast<short8v*>(&As[aoff]);
            #pragma unroll
            for (int nt = 0; nt < 8; ++nt) {
                int j = nt * 16 + c;
                int boff = (j * 64 + ks * 32 + g * 8) ^ ((j & 7) << 3);
                short8v bf = *reinterpret_cast<short8v*>(&Bs[boff]);
                acc[nt] = __builtin_amdgcn_mfma_f32_16x16x32_bf16(af, bf, acc[nt], 0, 0, 0);
            }
        }
        __syncthreads();
    }

    float al[8], ar[8];
    #pragma unroll
    for (int nt = 0; nt < 8; ++nt) {
        al[nt] = attn_l[nt * 16 + c];
        ar[nt] = attn_r[nt * 16 + c];
    }
    #pragma unroll
    for (int r = 0; r < 4; ++r) {
        int grow = row0 + wave * 16 + g * 4 + r;
        float sl = 0.f, sr = 0.f;
        #pragma unroll
        for (int nt = 0; nt < 8; ++nt) {
            float h = acc[nt][r];
            sl += h * al[nt];
            sr += h * ar[nt];
        }
        if (grow < N_NODES) {
            #pragma unroll
            for (int nt = 0; nt < 8; ++nt)
                Hb[(size_t)grow * F_OUT + nt * 16 + c] = f2bf(acc[nt][r]);
        }
        #pragma unroll
        for (int off = 1; off < 16; off <<= 1) {
            sl += __shfl_xor(sl, off);
            sr += __shfl_xor(sr, off);
        }
        if (c == 0 && grow < N_NODES) { el[grow] = sl; er[grow] = sr; }
    }
}

// ---------------- counting-sort CSR build ----------------
// level-1 histogram: bucket = dst >> 8
__global__ __launch_bounds__(256) void k_hist1(const int* __restrict__ dst,
                                               int* __restrict__ bcnt) {
    __shared__ int h[NBKT];
    int t = threadIdx.x;
    for (int i = t; i < NBKT; i += 256) h[i] = 0;
    __syncthreads();
    int e0  = blockIdx.x * 4096;
    int end = min(e0 + 4096, E_EDGES);
    for (int i = e0 + t; i < end; i += 256) atomicAdd(&h[dst[i] >> 8], 1);
    __syncthreads();
    for (int i = t; i < NBKT; i += 256) if (h[i]) atomicAdd(&bcnt[i], h[i]);
}

__global__ __launch_bounds__(512) void k_scan(const int* __restrict__ bcnt,
                                              int* __restrict__ bbase,
                                              int* __restrict__ bcur) {
    __shared__ int s[512];
    int t = threadIdx.x;
    int d = (t < NBKT) ? bcnt[t] : 0;
    s[t] = d;
    __syncthreads();
    for (int off = 1; off < 512; off <<= 1) {
        int v = (t >= off) ? s[t - off] : 0;
        __syncthreads();
        s[t] += v;
        __syncthreads();
    }
    if (t < NBKT) { int ex = s[t] - d; bbase[t] = ex; bcur[t] = ex; }
    if (t == NBKT - 1) bbase[NBKT] = s[t];
}

// level-1 scatter: block-aggregated cursors, packed (src | dstlocal<<17)
__global__ __launch_bounds__(256) void k_scatter1(const int* __restrict__ src,
                                                  const int* __restrict__ dst,
                                                  int* __restrict__ bcur,
                                                  unsigned int* __restrict__ epack) {
    __shared__ int h[NBKT];
    int t = threadIdx.x;
    for (int i = t; i < NBKT; i += 256) h[i] = 0;
    __syncthreads();
    int e0  = blockIdx.x * 4096;
    int end = min(e0 + 4096, E_EDGES);
    #pragma unroll
    for (int j = 0; j < 16; ++j) {
        int i = e0 + j * 256 + t;
        if (i < end) atomicAdd(&h[dst[i] >> 8], 1);
    }
    __syncthreads();
    for (int i = t; i < NBKT; i += 256) {
        int c = h[i];
        h[i] = c ? atomicAdd(&bcur[i], c) : 0;   // h[] becomes this block's cursor
    }
    __syncthreads();
    #pragma unroll
    for (int j = 0; j < 16; ++j) {
        int i = e0 + j * 256 + t;
        if (i < end) {
            int dv = dst[i];
            int p = atomicAdd(&h[dv >> 8], 1);
            epack[p] = (unsigned)src[i] | ((unsigned)(dv & 255) << 17);
        }
    }
}

// level-2: per-bucket LDS counting sort -> ESRC (dst-sorted), ROWPTR, DEG
__global__ __launch_bounds__(256) void k_sort2(const unsigned int* __restrict__ epack,
                                               const int* __restrict__ bbase,
                                               int* __restrict__ esrc,
                                               int* __restrict__ rowptr,
                                               int* __restrict__ deg) {
    __shared__ int hist[256], cur[256], s[256];
    __shared__ int obuf[OBCAP];
    int b = blockIdx.x, t = threadIdx.x;
    int base = bbase[b], end = bbase[b + 1];
    int cnt  = end - base;
    hist[t] = 0;
    __syncthreads();
    for (int i = t; i < cnt; i += 256) atomicAdd(&hist[epack[base + i] >> 17], 1);
    __syncthreads();
    int d = hist[t];
    s[t] = d;
    __syncthreads();
    for (int off = 1; off < 256; off <<= 1) {
        int v = (t >= off) ? s[t - off] : 0;
        __syncthreads();
        s[t] += v;
        __syncthreads();
    }
    int excl = s[t] - d;
    int n = b * 256 + t;
    if (n < N_NODES) { deg[n] = d; rowptr[n] = base + excl; }
    cur[t] = excl;
    __syncthreads();
    for (int i = t; i < cnt; i += 256) {
        unsigned e = epack[base + i];
        int p = atomicAdd(&cur[e >> 17], 1);
        if (p < OBCAP) obuf[p] = (int)(e & 0x1FFFFu);
    }
    __syncthreads();
    for (int i = t; i < cnt; i += 256) esrc[base + i] = obuf[i];
}

// ---------------- fused: online edge softmax + aggregation + head ----------------
__global__ __launch_bounds__(256) void agg_fused(const int* __restrict__ rowptr,
                                                 const int* __restrict__ deg,
                                                 const int* __restrict__ esrc,
                                                 const float* __restrict__ el,
                                                 const float* __restrict__ er,
                                                 const unsigned int* __restrict__ H2,
                                                 const float* __restrict__ bias,
                                                 const float* __restrict__ fcw,
                                                 const float* __restrict__ fcb,
                                                 float* __restrict__ out) {
    __shared__ float2 exbuf[4][64];
    int tid   = threadIdx.x;
    int wslot = tid >> 6;
    int wid   = (blockIdx.x * 256 + tid) >> 6;
    int lane  = tid & 63;
    if (wid >= N_NODES) return;
    int start = rowptr[wid];
    int dg    = deg[wid];
    float ern = er[wid];
    float m = -3.4e38f, ssum = 0.f;
    float2 acc = make_float2(0.f, 0.f);
    float2* eb = exbuf[wslot];

    for (int base = 0; base < dg; base += 64) {
        int cnt = min(64, dg - base);
        int sid = 0;
        float x = -3.4e38f;
        if (lane < cnt) {
            sid = esrc[start + base + lane];
            float tv = el[sid] + ern;
            x = tv > 0.f ? tv : 0.2f * tv;
        }
        // chunk max (butterfly)
        float cm = x;
        #pragma unroll
        for (int off = 32; off; off >>= 1) cm = fmaxf(cm, __shfl_xor(cm, off));
        float mn = fmaxf(m, cm);
        float r  = __expf(m - mn);           // 0 on first chunk, 1 if max unchanged
        float ex = (lane < cnt) ? __expf(x - mn) : 0.f;
        // chunk sum (butterfly)
        float cs = ex;
        #pragma unroll
        for (int off = 32; off; off >>= 1) cs += __shfl_xor(cs, off);
        ssum = ssum * r + cs;
        acc.x *= r; acc.y *= r;
        m = mn;
        eb[lane] = make_float2(ex, __int_as_float(sid));
        __builtin_amdgcn_wave_barrier();
        int q = 0;
        for (; q + 4 <= cnt; q += 4) {
            float2 p0 = eb[q+0], p1 = eb[q+1], p2 = eb[q+2], p3 = eb[q+3];
            unsigned v0 = H2[(size_t)__float_as_int(p0.y) * 64 + lane];
            unsigned v1 = H2[(size_t)__float_as_int(p1.y) * 64 + lane];
            unsigned v2 = H2[(size_t)__float_as_int(p2.y) * 64 + lane];
            unsigned v3 = H2[(size_t)__float_as_int(p3.y) * 64 + lane];
            acc.x += p0.x * __uint_as_float(v0 << 16);
            acc.y += p0.x * __uint_as_float(v0 & 0xffff0000u);
            acc.x += p1.x * __uint_as_float(v1 << 16);
            acc.y += p1.x * __uint_as_float(v1 & 0xffff0000u);
            acc.x += p2.x * __uint_as_float(v2 << 16);
            acc.y += p2.x * __uint_as_float(v2 & 0xffff0000u);
            acc.x += p3.x * __uint_as_float(v3 << 16);
            acc.y += p3.x * __uint_as_float(v3 & 0xffff0000u);
        }
        for (; q < cnt; ++q) {
            float2 p0 = eb[q];
            unsigned v0 = H2[(size_t)__float_as_int(p0.y) * 64 + lane];
            acc.x += p0.x * __uint_as_float(v0 << 16);
            acc.y += p0.x * __uint_as_float(v0 & 0xffff0000u);
        }
        __builtin_amdgcn_wave_barrier();
    }

    float scale = ssum > 0.f ? 1.f / ssum : 0.f;
    float2 bv = ((const float2*)bias)[lane];
    float v0 = fmaxf(acc.x * scale + bv.x, 0.f);
    float v1 = fmaxf(acc.y * scale + bv.y, 0.f);
    float4 wv = ((const float4*)fcw)[lane];
    float d0 = v0 * wv.x + v1 * wv.z;
    float d1 = v0 * wv.y + v1 * wv.w;
    #pragma unroll
    for (int off = 32; off; off >>= 1) {
        d0 += __shfl_down(d0, off);
        d1 += __shfl_down(d1, off);
    }
    if (lane == 0) {
        out[(size_t)wid * 2 + 0] = 1.f / (1.f + __expf(-(d0 + fcb[0])));
        out[(size_t)wid * 2 + 1] = 1.f / (1.f + __expf(-(d1 + fcb[1])));
    }
}

extern "C" void kernel_launch(void* const* d_in, const int* in_sizes, int n_in,
                              void* d_out, int out_size, void* d_ws, size_t ws_size,
                              hipStream_t stream) {
    const float* in_feat = (const float*)d_in[0];
    const float* W       = (const float*)d_in[1];
    const float* attn_l  = (const float*)d_in[2];
    const float* attn_r  = (const float*)d_in[3];
    const float* bias    = (const float*)d_in[4];
    const float* fc_w    = (const float*)d_in[5];
    const float* fc_b    = (const float*)d_in[6];
    const int*   src     = (const int*)d_in[7];
    const int*   dst     = (const int*)d_in[8];
    float* out = (float*)d_out;

    char* p = (char*)d_ws;
    unsigned short* HB = (unsigned short*)p; p += (size_t)N_NODES * F_OUT * sizeof(unsigned short);
    unsigned short* WT = (unsigned short*)p; p += (size_t)F_IN * F_OUT * sizeof(unsigned short);
    float* EL     = (float*)p; p += (size_t)N_NODES * sizeof(float);
    float* ER     = (float*)p; p += (size_t)N_NODES * sizeof(float);
    int*   DEG    = (int*)p;   p += (size_t)N_NODES * sizeof(int);
    int*   ROWPTR = (int*)p;   p += (size_t)N_NODES * sizeof(int);
    int*   BCNT   = (int*)p;   p += 512 * sizeof(int);
    int*   BBASE  = (int*)p;   p += 512 * sizeof(int);
    int*   BCUR   = (int*)p;   p += 512 * sizeof(int);
    unsigned int* EPACK = (unsigned int*)p; p += (size_t)E_EDGES * sizeof(unsigned int);
    int*   ESRC   = (int*)p;   p += (size_t)E_EDGES * sizeof(int);

    hipMemsetAsync(BCNT, 0, 512 * sizeof(int), stream);

    wcvt_kernel<<<(F_IN * F_OUT + 255) / 256, 256, 0, stream>>>(W, WT);
    gemm_mfma<<<(N_NODES + 63) / 64, 256, 0, stream>>>(in_feat, WT, attn_l, attn_r, HB, EL, ER);

    k_hist1   <<<NBKT, 256, 0, stream>>>(dst, BCNT);
    k_scan    <<<1, 512, 0, stream>>>(BCNT, BBASE, BCUR);
    k_scatter1<<<NBKT, 256, 0, stream>>>(src, dst, BCUR, EPACK);
    k_sort2   <<<NBKT, 256, 0, stream>>>(EPACK, BBASE, ESRC, ROWPTR, DEG);

    agg_fused<<<(N_NODES * 64 + 255) / 256, 256, 0, stream>>>(
        ROWPTR, DEG, ESRC, EL, ER, (const unsigned int*)HB, bias, fc_w, fc_b, out);
}

// Round 5
// 157.225 us; speedup vs baseline: 6.1235x; 1.0158x over previous
//
#include <hip/hip_runtime.h>
#include <cstdint>
#include <cstddef>

#define N_NODES 100000
#define E_EDGES 1600000
#define F_IN 256
#define F_OUT 128
#define NBKT 391      // ceil(N_NODES/256) buckets of 256 nodes
#define OBCAP 5120    // per-bucket LDS sort capacity

#define GLOBAL_AS __attribute__((address_space(1)))
#define LDS_AS    __attribute__((address_space(3)))

typedef __attribute__((ext_vector_type(8))) short  short8v;
typedef __attribute__((ext_vector_type(4))) float  float4v;

__device__ __forceinline__ unsigned short f2bf(float x) {
    union { float f; unsigned u; } v; v.f = x;
    unsigned r = v.u + 0x7fffu + ((v.u >> 16) & 1u);   // RNE
    return (unsigned short)(r >> 16);
}

__device__ __forceinline__ unsigned cvt_pk_bf16(float lo, float hi) {
    unsigned r;
    asm("v_cvt_pk_bf16_f32 %0, %1, %2" : "=v"(r) : "v"(lo), "v"(hi));
    return r;
}

// ---------------- W transpose+convert: Wt[j][k] = bf16(W[k][j]) ----------------
__global__ __launch_bounds__(256) void wcvt_kernel(const float* __restrict__ W,
                                                   unsigned short* __restrict__ Wt) {
    int t = blockIdx.x * 256 + threadIdx.x;
    if (t >= F_IN * F_OUT) return;
    int k = t >> 7, j = t & 127;
    Wt[j * F_IN + k] = f2bf(W[t]);
}

// ---------------- MFMA GEMM + fused el/er + bf16 H store ----------------
// A staged as f32 via global_load_lds (swizzle (r&15)<<2 words);
// B (Wt) staged as bf16 via global_load_lds (swizzle (j&7)<<3 ushorts).
__global__ __launch_bounds__(256) void gemm_mfma(const float* __restrict__ A,
                                                 const unsigned short* __restrict__ Wt,
                                                 const float* __restrict__ attn_l,
                                                 const float* __restrict__ attn_r,
                                                 unsigned short* __restrict__ Hb,
                                                 float* __restrict__ el,
                                                 float* __restrict__ er) {
    __shared__ float          Afs[64 * 64];    // 16 KB
    __shared__ unsigned short Bs[128 * 64];    // 16 KB
    int tid  = threadIdx.x;
    int wave = tid >> 6, lane = tid & 63;
    int g = lane >> 4, c = lane & 15;
    int row0 = blockIdx.x * 64;
    float4v acc[8] = {};

    // precompute per-thread staging indices (K-step invariant)
    int a_r[4], a_k[4], a_w[4];
    #pragma unroll
    for (int i = 0; i < 4; ++i) {
        int W_ = i * 1024 + tid * 4;           // linear LDS word slot
        int r  = W_ >> 6;
        a_w[i] = W_;
        a_r[i] = min(row0 + r, N_NODES - 1);   // clamp tail (dup row, masked later)
        a_k[i] = (W_ & 63) ^ ((r & 15) << 2);  // inverse-swizzled source k
    }
    int b_j[4], b_k[4], b_u[4];
    #pragma unroll
    for (int i = 0; i < 4; ++i) {
        int U_ = i * 2048 + tid * 8;           // linear LDS ushort slot
        int j  = U_ >> 6;
        b_u[i] = U_;
        b_j[i] = j;
        b_k[i] = (U_ & 63) ^ ((j & 7) << 3);
    }

    for (int k0 = 0; k0 < F_IN; k0 += 64) {
        #pragma unroll
        for (int i = 0; i < 4; ++i) {
            __builtin_amdgcn_global_load_lds(
                (const GLOBAL_AS unsigned int*)(A + (size_t)a_r[i] * F_IN + k0 + a_k[i]),
                (LDS_AS unsigned int*)&Afs[a_w[i]], 16, 0, 0);
        }
        #pragma unroll
        for (int i = 0; i < 4; ++i) {
            __builtin_amdgcn_global_load_lds(
                (const GLOBAL_AS unsigned int*)(Wt + (size_t)b_j[i] * F_IN + k0 + b_k[i]),
                (LDS_AS unsigned int*)&Bs[b_u[i]], 16, 0, 0);
        }
        __syncthreads();
        int arow = wave * 16 + c;
        int aswz = (arow & 15) << 2;
        #pragma unroll
        for (int ks = 0; ks < 2; ++ks) {
            int woff = arow * 64 + ks * 32 + g * 8;
            float4 a0 = *reinterpret_cast<float4*>(&Afs[(woff)     ^ aswz]);
            float4 a1 = *reinterpret_cast<float4*>(&Afs[(woff + 4) ^ aswz]);
            unsigned u[4];
            u[0] = cvt_pk_bf16(a0.x, a0.y);
            u[1] = cvt_pk_bf16(a0.z, a0.w);
            u[2] = cvt_pk_bf16(a1.x, a1.y);
            u[3] = cvt_pk_bf16(a1.z, a1.w);
            short8v af = *reinterpret_cast<short8v*>(u);
            #pragma unroll
            for (int nt = 0; nt < 8; ++nt) {
                int j = nt * 16 + c;
                int boff = (j * 64 + ks * 32 + g * 8) ^ ((j & 7) << 3);
                short8v bf = *reinterpret_cast<short8v*>(&Bs[boff]);
                acc[nt] = __builtin_amdgcn_mfma_f32_16x16x32_bf16(af, bf, acc[nt], 0, 0, 0);
            }
        }
        __syncthreads();
    }

    float al[8], ar[8];
    #pragma unroll
    for (int nt = 0; nt < 8; ++nt) {
        al[nt] = attn_l[nt * 16 + c];
        ar[nt] = attn_r[nt * 16 + c];
    }
    #pragma unroll
    for (int r = 0; r < 4; ++r) {
        int grow = row0 + wave * 16 + g * 4 + r;
        float sl = 0.f, sr = 0.f;
        #pragma unroll
        for (int nt = 0; nt < 8; ++nt) {
            float h = acc[nt][r];
            sl += h * al[nt];
            sr += h * ar[nt];
        }
        if (grow < N_NODES) {
            #pragma unroll
            for (int nt = 0; nt < 8; ++nt)
                Hb[(size_t)grow * F_OUT + nt * 16 + c] = f2bf(acc[nt][r]);
        }
        #pragma unroll
        for (int off = 1; off < 16; off <<= 1) {
            sl += __shfl_xor(sl, off);
            sr += __shfl_xor(sr, off);
        }
        if (c == 0 && grow < N_NODES) { el[grow] = sl; er[grow] = sr; }
    }
}

// ---------------- counting-sort CSR build ----------------
__global__ __launch_bounds__(256) void k_hist1(const int* __restrict__ dst,
                                               int* __restrict__ bcnt) {
    __shared__ int h[NBKT];
    int t = threadIdx.x;
    for (int i = t; i < NBKT; i += 256) h[i] = 0;
    __syncthreads();
    int e0  = blockIdx.x * 4096;
    int end = min(e0 + 4096, E_EDGES);
    for (int i = e0 + t; i < end; i += 256) atomicAdd(&h[dst[i] >> 8], 1);
    __syncthreads();
    for (int i = t; i < NBKT; i += 256) if (h[i]) atomicAdd(&bcnt[i], h[i]);
}

__global__ __launch_bounds__(512) void k_scan(const int* __restrict__ bcnt,
                                              int* __restrict__ bbase,
                                              int* __restrict__ bcur) {
    __shared__ int s[512];
    int t = threadIdx.x;
    int d = (t < NBKT) ? bcnt[t] : 0;
    s[t] = d;
    __syncthreads();
    for (int off = 1; off < 512; off <<= 1) {
        int v = (t >= off) ? s[t - off] : 0;
        __syncthreads();
        s[t] += v;
        __syncthreads();
    }
    if (t < NBKT) { int ex = s[t] - d; bbase[t] = ex; bcur[t] = ex; }
    if (t == NBKT - 1) bbase[NBKT] = s[t];
}

__global__ __launch_bounds__(256) void k_scatter1(const int* __restrict__ src,
                                                  const int* __restrict__ dst,
                                                  int* __restrict__ bcur,
                                                  unsigned int* __restrict__ epack) {
    __shared__ int h[NBKT];
    int t = threadIdx.x;
    for (int i = t; i < NBKT; i += 256) h[i] = 0;
    __syncthreads();
    int e0  = blockIdx.x * 4096;
    int end = min(e0 + 4096, E_EDGES);
    #pragma unroll
    for (int j = 0; j < 16; ++j) {
        int i = e0 + j * 256 + t;
        if (i < end) atomicAdd(&h[dst[i] >> 8], 1);
    }
    __syncthreads();
    for (int i = t; i < NBKT; i += 256) {
        int c = h[i];
        h[i] = c ? atomicAdd(&bcur[i], c) : 0;
    }
    __syncthreads();
    #pragma unroll
    for (int j = 0; j < 16; ++j) {
        int i = e0 + j * 256 + t;
        if (i < end) {
            int dv = dst[i];
            int p = atomicAdd(&h[dv >> 8], 1);
            epack[p] = (unsigned)src[i] | ((unsigned)(dv & 255) << 17);
        }
    }
}

__global__ __launch_bounds__(256) void k_sort2(const unsigned int* __restrict__ epack,
                                               const int* __restrict__ bbase,
                                               int* __restrict__ esrc,
                                               int* __restrict__ rowptr,
                                               int* __restrict__ deg) {
    __shared__ int hist[256], cur[256], s[256];
    __shared__ int obuf[OBCAP];
    int b = blockIdx.x, t = threadIdx.x;
    int base = bbase[b], end = bbase[b + 1];
    int cnt  = end - base;
    hist[t] = 0;
    __syncthreads();
    for (int i = t; i < cnt; i += 256) atomicAdd(&hist[epack[base + i] >> 17], 1);
    __syncthreads();
    int d = hist[t];
    s[t] = d;
    __syncthreads();
    for (int off = 1; off < 256; off <<= 1) {
        int v = (t >= off) ? s[t - off] : 0;
        __syncthreads();
        s[t] += v;
        __syncthreads();
    }
    int excl = s[t] - d;
    int n = b * 256 + t;
    if (n < N_NODES) { deg[n] = d; rowptr[n] = base + excl; }
    cur[t] = excl;
    __syncthreads();
    for (int i = t; i < cnt; i += 256) {
        unsigned e = epack[base + i];
        int p = atomicAdd(&cur[e >> 17], 1);
        if (p < OBCAP) obuf[p] = (int)(e & 0x1FFFFu);
    }
    __syncthreads();
    for (int i = t; i < cnt; i += 256) esrc[base + i] = obuf[i];
}

// ---------------- fused: online edge softmax + aggregation + head ----------------
__global__ __launch_bounds__(256) void agg_fused(const int* __restrict__ rowptr,
                                                 const int* __restrict__ deg,
                                                 const int* __restrict__ esrc,
                                                 const float* __restrict__ el,
                                                 const float* __restrict__ er,
                                                 const char* __restrict__ Hc,
                                                 const float* __restrict__ bias,
                                                 const float* __restrict__ fcw,
                                                 const float* __restrict__ fcb,
                                                 float* __restrict__ out) {
    __shared__ float2 exbuf[4][64];
    int tid   = threadIdx.x;
    int wslot = tid >> 6;
    int wid   = (blockIdx.x * 256 + tid) >> 6;
    int lane  = tid & 63;
    if (wid >= N_NODES) return;
    int start = rowptr[wid];
    int dg    = deg[wid];
    float ern = er[wid];
    float m = -3.4e38f, ssum = 0.f;
    float2 acc = make_float2(0.f, 0.f);
    float2* eb = exbuf[wslot];
    unsigned lane4 = (unsigned)lane << 2;

    for (int base = 0; base < dg; base += 64) {
        int cnt = min(64, dg - base);
        unsigned rowb = 0;
        float x = -3.4e38f;
        if (lane < cnt) {
            int sid = esrc[start + base + lane];
            float tv = el[(unsigned)sid] + ern;
            x = tv > 0.f ? tv : 0.2f * tv;
            rowb = (unsigned)sid << 8;          // byte offset of H row
        }
        float cm = x;
        #pragma unroll
        for (int off = 32; off; off >>= 1) cm = fmaxf(cm, __shfl_xor(cm, off));
        float mn = fmaxf(m, cm);
        float r  = __expf(m - mn);
        float ex = (lane < cnt) ? __expf(x - mn) : 0.f;
        float cs = ex;
        #pragma unroll
        for (int off = 32; off; off >>= 1) cs += __shfl_xor(cs, off);
        ssum = ssum * r + cs;
        acc.x *= r; acc.y *= r;
        m = mn;
        eb[lane] = make_float2(ex, __uint_as_float(rowb));
        __builtin_amdgcn_wave_barrier();
        int q = 0;
        for (; q + 4 <= cnt; q += 4) {
            float2 p0 = eb[q+0], p1 = eb[q+1], p2 = eb[q+2], p3 = eb[q+3];
            unsigned v0 = *(const unsigned*)(Hc + (__float_as_uint(p0.y) + lane4));
            unsigned v1 = *(const unsigned*)(Hc + (__float_as_uint(p1.y) + lane4));
            unsigned v2 = *(const unsigned*)(Hc + (__float_as_uint(p2.y) + lane4));
            unsigned v3 = *(const unsigned*)(Hc + (__float_as_uint(p3.y) + lane4));
            acc.x += p0.x * __uint_as_float(v0 << 16);
            acc.y += p0.x * __uint_as_float(v0 & 0xffff0000u);
            acc.x += p1.x * __uint_as_float(v1 << 16);
            acc.y += p1.x * __uint_as_float(v1 & 0xffff0000u);
            acc.x += p2.x * __uint_as_float(v2 << 16);
            acc.y += p2.x * __uint_as_float(v2 & 0xffff0000u);
            acc.x += p3.x * __uint_as_float(v3 << 16);
            acc.y += p3.x * __uint_as_float(v3 & 0xffff0000u);
        }
        for (; q < cnt; ++q) {
            float2 p0 = eb[q];
            unsigned v0 = *(const unsigned*)(Hc + (__float_as_uint(p0.y) + lane4));
            acc.x += p0.x * __uint_as_float(v0 << 16);
            acc.y += p0.x * __uint_as_float(v0 & 0xffff0000u);
        }
        __builtin_amdgcn_wave_barrier();
    }

    float scale = ssum > 0.f ? 1.f / ssum : 0.f;
    float2 bv = ((const float2*)bias)[lane];
    float v0 = fmaxf(acc.x * scale + bv.x, 0.f);
    float v1 = fmaxf(acc.y * scale + bv.y, 0.f);
    float4 wv = ((const float4*)fcw)[lane];
    float d0 = v0 * wv.x + v1 * wv.z;
    float d1 = v0 * wv.y + v1 * wv.w;
    #pragma unroll
    for (int off = 32; off; off >>= 1) {
        d0 += __shfl_down(d0, off);
        d1 += __shfl_down(d1, off);
    }
    if (lane == 0) {
        out[(size_t)wid * 2 + 0] = 1.f / (1.f + __expf(-(d0 + fcb[0])));
        out[(size_t)wid * 2 + 1] = 1.f / (1.f + __expf(-(d1 + fcb[1])));
    }
}

extern "C" void kernel_launch(void* const* d_in, const int* in_sizes, int n_in,
                              void* d_out, int out_size, void* d_ws, size_t ws_size,
                              hipStream_t stream) {
    const float* in_feat = (const float*)d_in[0];
    const float* W       = (const float*)d_in[1];
    const float* attn_l  = (const float*)d_in[2];
    const float* attn_r  = (const float*)d_in[3];
    const float* bias    = (const float*)d_in[4];
    const float* fc_w    = (const float*)d_in[5];
    const float* fc_b    = (const float*)d_in[6];
    const int*   src     = (const int*)d_in[7];
    const int*   dst     = (const int*)d_in[8];
    float* out = (float*)d_out;

    char* p = (char*)d_ws;
    unsigned short* HB = (unsigned short*)p; p += (size_t)N_NODES * F_OUT * sizeof(unsigned short);
    unsigned short* WT = (unsigned short*)p; p += (size_t)F_IN * F_OUT * sizeof(unsigned short);
    float* EL     = (float*)p; p += (size_t)N_NODES * sizeof(float);
    float* ER     = (float*)p; p += (size_t)N_NODES * sizeof(float);
    int*   DEG    = (int*)p;   p += (size_t)N_NODES * sizeof(int);
    int*   ROWPTR = (int*)p;   p += (size_t)N_NODES * sizeof(int);
    int*   BCNT   = (int*)p;   p += 512 * sizeof(int);
    int*   BBASE  = (int*)p;   p += 512 * sizeof(int);
    int*   BCUR   = (int*)p;   p += 512 * sizeof(int);
    unsigned int* EPACK = (unsigned int*)p; p += (size_t)E_EDGES * sizeof(unsigned int);
    int*   ESRC   = (int*)p;   p += (size_t)E_EDGES * sizeof(int);

    hipMemsetAsync(BCNT, 0, 512 * sizeof(int), stream);

    wcvt_kernel<<<(F_IN * F_OUT + 255) / 256, 256, 0, stream>>>(W, WT);
    gemm_mfma<<<(N_NODES + 63) / 64, 256, 0, stream>>>(in_feat, WT, attn_l, attn_r, HB, EL, ER);

    k_hist1   <<<NBKT, 256, 0, stream>>>(dst, BCNT);
    k_scan    <<<1, 512, 0, stream>>>(BCNT, BBASE, BCUR);
    k_scatter1<<<NBKT, 256, 0, stream>>>(src, dst, BCUR, EPACK);
    k_sort2   <<<NBKT, 256, 0, stream>>>(EPACK, BBASE, ESRC, ROWPTR, DEG);

    agg_fused<<<(N_NODES * 64 + 255) / 256, 256, 0, stream>>>(
        ROWPTR, DEG, ESRC, EL, ER, (const char*)HB, bias, fc_w, fc_b, out);
}